// Round 2
// baseline (339.548 us; speedup 1.0000x reference)
//
#include <hip/hip_runtime.h>

// NRI edge-MLP encoder, fused single kernel (NO workspace):
// out[b,e,:] = relu(concat(x[b,send(e)], x[b,recv(e)]) @ W1^T + b1) @ W2^T + b2
// B=8, N=256, E=65280, n_in=64, n_hid=128, n_out=64.
// edge e: recv = e/255, k = e%255, send = k + (k >= recv)
//
// Round-1 post-mortem: fused version spilled. VGPR_Count=128 while live set
// ~200 (w1f[4][8]=128 VGPRs + fp32 conversion transients) -> ~71MB scratch
// writes + ~39MB scratch reads per dispatch (WRITE_SIZE 202MB vs 130.7MB
// output), kernel 155us latency-bound. LDS (64KB/block) caps occupancy at
// 2 blocks/CU = 2 waves/EU regardless, so spilling to fit 128 VGPRs bought
// nothing. Fix: amdgpu_waves_per_eu(2,2) forces the 256-VGPR budget, and
// W-fragment conversion is grouped (8 frags = 64 VGPR in flight) with
// sched_barrier fences so the scheduler can't hoist all fp32 loads at once.

using frag_t  = __attribute__((ext_vector_type(8))) short;          // 8 bf16 = 4 VGPRs
using f32x4   = __attribute__((ext_vector_type(4))) float;
using ushort8 = __attribute__((ext_vector_type(8))) unsigned short;

__device__ inline unsigned short f2bf(float f) {
    union { float f; unsigned u; } v; v.f = f;
    unsigned r = v.u + 0x7fffu + ((v.u >> 16) & 1u);   // RTNE
    return (unsigned short)(r >> 16);
}

__device__ inline ushort8 pack8(f32x4 a, f32x4 b) {
    ushort8 o;
    o[0] = f2bf(a[0]); o[1] = f2bf(a[1]); o[2] = f2bf(a[2]); o[3] = f2bf(a[3]);
    o[4] = f2bf(b[0]); o[5] = f2bf(b[1]); o[6] = f2bf(b[2]); o[7] = f2bf(b[3]);
    return o;
}

// grid 2040 = 8 batches x 255 blocks x 256 edges. Wave owns 64 edges, no barriers
// (per-wave LDS slab; compiler handles same-wave ds ordering via lgkmcnt).
// LDS: per-wave 16 KB A/H buffer, row-major 128-elem rows, 16B chunks XOR-swizzled
// (slot = chunk ^ (row&7)) for conflict-free ds_read_b128 fragments. W1/W2
// fragments converted fp32->bf16 in-register (L2-resident broadcast reads),
// reused over 4 tiles. Layer2 computes out^T = W2 @ H^T -> C rows = 4
// consecutive out-features -> direct float4 stores.
__global__ __launch_bounds__(256, 2)
__attribute__((amdgpu_waves_per_eu(2, 2)))
void nri_mlp_fused(const float* __restrict__ x,
                   const float* __restrict__ W1,
                   const float* __restrict__ b1,
                   const float* __restrict__ W2,
                   const float* __restrict__ b2,
                   float* __restrict__ out) {
    __shared__ unsigned short Sh[4][64 * 128];   // 64 KB: 4 waves x (64 edges x 128)

    const int tid  = threadIdx.x;
    const int wave = tid >> 6;
    const int lane = tid & 63;
    const int quad = lane >> 4;
    const int n16  = lane & 15;

    const int bx = blockIdx.x;
    const int b  = bx / 255;
    const int eb = (bx - b * 255) * 256;
    const int e0 = eb + wave * 64;               // this wave's 64 edges

    const float* xb = x + b * (256 * 64);
    unsigned short* Aw = &Sh[wave][0];

    // ---- stage A: fp32 gather -> bf16 -> swizzled LDS. lane l handles rows
    // i*4 + l/16, slot l%16; slot holds data chunk slot^(row&7). All 16 loads
    // issued before any conversion (128-VGPR transient; nothing else live yet).
    {
        const int r4   = lane >> 4;      // 0..3
        const int slot = lane & 15;
        f32x4 va[16], vb[16];
        #pragma unroll
        for (int i = 0; i < 16; ++i) {
            int rr   = i * 4 + r4;                       // local edge row 0..63
            int e    = e0 + rr;
            int recv = e / 255;
            int kk   = e - recv * 255;
            int send = kk + (kk >= recv ? 1 : 0);
            int c    = slot ^ (rr & 7);                  // data chunk stored at this slot
            int node = (c < 8) ? send : recv;
            const float* src = xb + node * 64 + (c & 7) * 8;   // 32B-aligned
            va[i] = *(const f32x4*)src;
            vb[i] = *(const f32x4*)(src + 4);
        }
        #pragma unroll
        for (int i = 0; i < 16; ++i) {
            int rr = i * 4 + r4;
            *(ushort8*)&Aw[rr * 128 + slot * 8] = pack8(va[i], vb[i]);
        }
    }
    __builtin_amdgcn_sched_barrier(0);   // staging transients die here

    // ---- W1 fragments -> registers (B-operand: lane n16 = W1 row, k-run).
    // fp32->bf16 per ks-group of 8 frags: 64-VGPR transient, fenced.
    frag_t w1f[4][8];
    #pragma unroll
    for (int ks = 0; ks < 4; ++ks) {
        f32x4 t0[8], t1[8];
        #pragma unroll
        for (int c = 0; c < 8; ++c) {
            const float* s = W1 + (c * 16 + n16) * 128 + ks * 32 + quad * 8;
            t0[c] = *(const f32x4*)s;
            t1[c] = *(const f32x4*)(s + 4);
        }
        #pragma unroll
        for (int c = 0; c < 8; ++c) {
            union { ushort8 u; frag_t f; } vv;
            vv.u = pack8(t0[c], t1[c]);
            w1f[ks][c] = vv.f;
        }
        __builtin_amdgcn_sched_barrier(0);
    }

    float b1v[8];
    #pragma unroll
    for (int c = 0; c < 8; ++c) b1v[c] = b1[c * 16 + n16];

    // ---- phase 1: H = relu(A @ W1^T + b1), tile-by-tile, H overwrites A rows ----
    #pragma unroll
    for (int t = 0; t < 4; ++t) {
        frag_t af[4];
        #pragma unroll
        for (int ks = 0; ks < 4; ++ks) {
            int r    = t * 16 + n16;
            int slot = (ks * 4 + quad) ^ (r & 7);
            af[ks] = *(const frag_t*)&Aw[r * 128 + slot * 8];
        }
        f32x4 acc[8];
        #pragma unroll
        for (int c = 0; c < 8; ++c) acc[c] = (f32x4){0.f, 0.f, 0.f, 0.f};
        #pragma unroll
        for (int ks = 0; ks < 4; ++ks)
            #pragma unroll
            for (int c = 0; c < 8; ++c)
                acc[c] = __builtin_amdgcn_mfma_f32_16x16x32_bf16(af[ks], w1f[ks][c], acc[c], 0, 0, 0);

        // C-layout: col = n16 (hid feat c*16+n16), row = quad*4+r_i (edge row)
        #pragma unroll
        for (int c = 0; c < 8; ++c) {
            float bv = b1v[c];
            #pragma unroll
            for (int ri = 0; ri < 4; ++ri) {
                float v = acc[c][ri] + bv;
                v = v > 0.f ? v : 0.f;
                int row  = t * 16 + quad * 4 + ri;
                int k    = c * 16 + n16;
                int slot = (k >> 3) ^ (row & 7);
                Aw[row * 128 + slot * 8 + (n16 & 7)] = f2bf(v);
            }
        }
    }
    __builtin_amdgcn_sched_barrier(0);   // w1f dies here

    // ---- phase 2: out^T = W2 @ H^T. A-operand = W2 rows, B-operand = H rows.
    // W2 conversion grouped: 2 groups of 8 frags (64-VGPR transient).
    frag_t w2f[4][4];
    #pragma unroll
    for (int g = 0; g < 2; ++g) {
        f32x4 t0[8], t1[8];
        #pragma unroll
        for (int j = 0; j < 8; ++j) {
            int ks = g * 2 + (j >> 2);
            int c2 = j & 3;
            const float* s = W2 + (c2 * 16 + n16) * 128 + ks * 32 + quad * 8;
            t0[j] = *(const f32x4*)s;
            t1[j] = *(const f32x4*)(s + 4);
        }
        #pragma unroll
        for (int j = 0; j < 8; ++j) {
            int ks = g * 2 + (j >> 2);
            int c2 = j & 3;
            union { ushort8 u; frag_t f; } vv;
            vv.u = pack8(t0[j], t1[j]);
            w2f[ks][c2] = vv.f;
        }
        __builtin_amdgcn_sched_barrier(0);
    }

    float b2v[4][4];
    #pragma unroll
    for (int c2 = 0; c2 < 4; ++c2)
        #pragma unroll
        for (int ri = 0; ri < 4; ++ri)
            b2v[c2][ri] = b2[c2 * 16 + quad * 4 + ri];

    #pragma unroll
    for (int t = 0; t < 4; ++t) {
        frag_t hf[4];
        #pragma unroll
        for (int ks = 0; ks < 4; ++ks) {
            int r    = t * 16 + n16;
            int slot = (ks * 4 + quad) ^ (r & 7);
            hf[ks] = *(const frag_t*)&Aw[r * 128 + slot * 8];
        }
        f32x4 acc2[4];
        #pragma unroll
        for (int c2 = 0; c2 < 4; ++c2) acc2[c2] = (f32x4){0.f, 0.f, 0.f, 0.f};
        #pragma unroll
        for (int ks = 0; ks < 4; ++ks)
            #pragma unroll
            for (int c2 = 0; c2 < 4; ++c2)
                acc2[c2] = __builtin_amdgcn_mfma_f32_16x16x32_bf16(w2f[ks][c2], hf[ks], acc2[c2], 0, 0, 0);

        // C-layout: col = n16 = edge, row = quad*4+reg = out-feature -> float4 store
        float* ob = out + ((long)b * 65280 + e0 + t * 16 + n16) * 64;
        #pragma unroll
        for (int c2 = 0; c2 < 4; ++c2) {
            f32x4 v;
            #pragma unroll
            for (int ri = 0; ri < 4; ++ri) v[ri] = acc2[c2][ri] + b2v[c2][ri];
            *(f32x4*)&ob[c2 * 16 + quad * 4] = v;
        }
    }
}

extern "C" void kernel_launch(void* const* d_in, const int* in_sizes, int n_in,
                              void* d_out, int out_size, void* d_ws, size_t ws_size,
                              hipStream_t stream) {
    const float* x  = (const float*)d_in[0];
    // d_in[1] = rel_rec, d_in[2] = rel_send: one-hot incidence, replaced by index math
    const float* W1 = (const float*)d_in[3];
    const float* b1 = (const float*)d_in[4];
    const float* W2 = (const float*)d_in[5];
    const float* b2 = (const float*)d_in[6];
    (void)d_ws; (void)ws_size; (void)in_sizes; (void)n_in; (void)out_size;
    float* out = (float*)d_out;

    nri_mlp_fused<<<2040, 256, 0, stream>>>(x, W1, b1, W2, b2, out);
}

// Round 3
// 313.210 us; speedup vs baseline: 1.0841x; 1.0841x over previous
//
#include <hip/hip_runtime.h>

// NRI edge-MLP encoder, fused single kernel (NO workspace):
// out[b,e,:] = relu(concat(x[b,send(e)], x[b,recv(e)]) @ W1^T + b1) @ W2^T + b2
// B=8, N=256, E=65280, n_in=64, n_hid=128, n_out=64.
// edge e: recv = e/255, k = e%255, send = k + (k >= recv)
//
// Round-2 post-mortem: spill was DEMAND overflow (live set ~330 > 256 unified
// VGPR+AGPR budget): w1f 128 + fp32 staging transients 128 + acc 32 + addr.
// WRITE_SIZE = output + ~97MB scratch. Fix is structural:
//  (a) A-tile LDS staging deleted -- zero reuse, fragments load DIRECT from
//      global (send chunks = consecutive 128B node rows, recv chunks =
//      broadcast; all L1/L2-resident). Kills the 128-reg staging transient.
//  (b) W1/W2 converted fp32->bf16 ONCE per block, cooperatively, into
//      swizzled LDS (slot = chunk ^ (row&7)); waves ds_read bf16 fragments.
//      Kills the per-wave fp32 W transient, amortizes conversion 4x.
//  (c) per-tile fusion: phase1(t) -> H(16 rows, 4KB LDS) -> phase2(t) ->
//      store. w2f re-read per ks (16-reg transient, not 64 resident).
// Peak live set ~210 regs. LDS = 32K(W1)+16K(W2)+4x4K(H) = 64KB -> 2 blk/CU.

using frag_t  = __attribute__((ext_vector_type(8))) short;          // 8 bf16 = 4 VGPRs
using f32x4   = __attribute__((ext_vector_type(4))) float;
using ushort8 = __attribute__((ext_vector_type(8))) unsigned short;

__device__ inline unsigned short f2bf(float f) {
    union { float f; unsigned u; } v; v.f = f;
    unsigned r = v.u + 0x7fffu + ((v.u >> 16) & 1u);   // RTNE
    return (unsigned short)(r >> 16);
}

__device__ inline ushort8 pack8(f32x4 a, f32x4 b) {
    ushort8 o;
    o[0] = f2bf(a[0]); o[1] = f2bf(a[1]); o[2] = f2bf(a[2]); o[3] = f2bf(a[3]);
    o[4] = f2bf(b[0]); o[5] = f2bf(b[1]); o[6] = f2bf(b[2]); o[7] = f2bf(b[3]);
    return o;
}

__device__ inline frag_t packfrag(f32x4 a, f32x4 b) {
    union { ushort8 u; frag_t f; } v; v.u = pack8(a, b); return v.f;
}

// grid 2040 = 8 batches x 255 blocks x 256 edges; wave owns 64 edges.
// One __syncthreads after the cooperative W stage; everything else is
// per-wave (same-wave LDS ops complete in order -- verified by the round-0
// kernel which relied on the same property).
__global__ __launch_bounds__(256, 2)
void nri_mlp_fused(const float* __restrict__ x,
                   const float* __restrict__ W1,
                   const float* __restrict__ b1,
                   const float* __restrict__ W2,
                   const float* __restrict__ b2,
                   float* __restrict__ out) {
    __shared__ unsigned short W1s[128 * 128];    // 32 KB, swizzled bf16
    __shared__ unsigned short W2s[64 * 128];     // 16 KB, swizzled bf16
    __shared__ unsigned short Hs[4][16 * 128];   // 16 KB: per-wave 16-row H tile

    const int tid  = threadIdx.x;
    const int wave = tid >> 6;
    const int lane = tid & 63;
    const int quad = lane >> 4;
    const int n16  = lane & 15;

    const int bx = blockIdx.x;
    const int b  = bx / 255;
    const int eb = (bx - b * 255) * 256;
    const int e0 = eb + wave * 64;               // this wave's 64 edges

    const float* xb = x + b * (256 * 64);

    // ---- cooperative W1/W2 stage: fp32 -> bf16 -> swizzled LDS ----
    // chunk = 8 elems (16B bf16). Data chunk c of row r stored at slot c^(r&7).
    #pragma unroll
    for (int i = 0; i < 8; ++i) {                // W1: 2048 chunks / 256 thr
        int cid  = tid + i * 256;
        int row  = cid >> 4;                     // 0..127
        int c    = cid & 15;
        int slot = c ^ (row & 7);
        const float* s = W1 + row * 128 + c * 8;
        *(ushort8*)&W1s[row * 128 + slot * 8] =
            pack8(*(const f32x4*)s, *(const f32x4*)(s + 4));
    }
    #pragma unroll
    for (int i = 0; i < 4; ++i) {                // W2: 1024 chunks / 256 thr
        int cid  = tid + i * 256;
        int row  = cid >> 4;                     // 0..63
        int c    = cid & 15;
        int slot = c ^ (row & 7);
        const float* s = W2 + row * 128 + c * 8;
        *(ushort8*)&W2s[row * 128 + slot * 8] =
            pack8(*(const f32x4*)s, *(const f32x4*)(s + 4));
    }
    __syncthreads();

    // ---- w1f resident (the ONE big register block): B-operand frags,
    // row = c*16+n16 (hid feat), k = ks*32 + quad*8 ----
    frag_t w1f[4][8];
    #pragma unroll
    for (int ks = 0; ks < 4; ++ks)
        #pragma unroll
        for (int c = 0; c < 8; ++c) {
            int row  = c * 16 + n16;
            int slot = (ks * 4 + quad) ^ (row & 7);
            w1f[ks][c] = *(const frag_t*)&W1s[row * 128 + slot * 8];
        }

    float b1v[8];
    #pragma unroll
    for (int c = 0; c < 8; ++c) b1v[c] = b1[c * 16 + n16];
    float b2v[4][4];
    #pragma unroll
    for (int c2 = 0; c2 < 4; ++c2)
        #pragma unroll
        for (int ri = 0; ri < 4; ++ri)
            b2v[c2][ri] = b2[c2 * 16 + quad * 4 + ri];

    unsigned short* Hw = &Hs[wave][0];

    #pragma unroll 1   // contain register pressure: no cross-tile hoisting
    for (int t = 0; t < 4; ++t) {
        // A-operand row for this lane: edge e, features k = ks*32 + quad*8.
        // chunk = ks*4+quad: chunks 0..7 = sender feats, 8..15 = receiver.
        int e    = e0 + t * 16 + n16;
        int recv = e / 255;
        int kk   = e - recv * 255;
        int send = kk + (kk >= recv ? 1 : 0);

        frag_t af[4];
        #pragma unroll
        for (int ks = 0; ks < 4; ++ks) {
            int node = (ks < 2) ? send : recv;                    // ks<2 <=> chunk<8
            const float* s = xb + node * 64 + ((ks & 1) * 4 + quad) * 8;
            af[ks] = packfrag(*(const f32x4*)s, *(const f32x4*)(s + 4));
        }

        // ---- phase 1: H-tile = relu(A @ W1^T + b1) ----
        f32x4 acc[8];
        #pragma unroll
        for (int c = 0; c < 8; ++c) acc[c] = (f32x4){0.f, 0.f, 0.f, 0.f};
        #pragma unroll
        for (int ks = 0; ks < 4; ++ks)
            #pragma unroll
            for (int c = 0; c < 8; ++c)
                acc[c] = __builtin_amdgcn_mfma_f32_16x16x32_bf16(af[ks], w1f[ks][c], acc[c], 0, 0, 0);

        // C-layout: col = n16 (hid feat c*16+n16), row = quad*4+ri (edge row 0..15)
        #pragma unroll
        for (int c = 0; c < 8; ++c) {
            float bv = b1v[c];
            #pragma unroll
            for (int ri = 0; ri < 4; ++ri) {
                float v = acc[c][ri] + bv;
                v = v > 0.f ? v : 0.f;
                int row  = quad * 4 + ri;
                int k    = c * 16 + n16;
                int slot = (k >> 3) ^ (row & 7);
                Hw[row * 128 + slot * 8 + (n16 & 7)] = f2bf(v);
            }
        }

        // ---- phase 2: out-tile^T = W2 @ H^T (w2f streamed from LDS) ----
        f32x4 acc2[4];
        #pragma unroll
        for (int c2 = 0; c2 < 4; ++c2) acc2[c2] = (f32x4){0.f, 0.f, 0.f, 0.f};
        #pragma unroll
        for (int ks = 0; ks < 4; ++ks) {
            int hslot = (ks * 4 + quad) ^ (n16 & 7);   // H row = n16; W2 row&7 = n16&7
            frag_t hf = *(const frag_t*)&Hw[n16 * 128 + hslot * 8];
            #pragma unroll
            for (int c2 = 0; c2 < 4; ++c2) {
                int row = c2 * 16 + n16;
                frag_t w2 = *(const frag_t*)&W2s[row * 128 + hslot * 8];
                acc2[c2] = __builtin_amdgcn_mfma_f32_16x16x32_bf16(w2, hf, acc2[c2], 0, 0, 0);
            }
        }

        // C-layout: col = n16 = edge, row = quad*4+ri = out-feature -> float4 store
        float* ob = out + ((long)b * 65280 + e0 + t * 16 + n16) * 64;
        #pragma unroll
        for (int c2 = 0; c2 < 4; ++c2) {
            f32x4 v;
            #pragma unroll
            for (int ri = 0; ri < 4; ++ri) v[ri] = acc2[c2][ri] + b2v[c2][ri];
            *(f32x4*)&ob[c2 * 16 + quad * 4] = v;
        }
    }
}

extern "C" void kernel_launch(void* const* d_in, const int* in_sizes, int n_in,
                              void* d_out, int out_size, void* d_ws, size_t ws_size,
                              hipStream_t stream) {
    const float* x  = (const float*)d_in[0];
    // d_in[1] = rel_rec, d_in[2] = rel_send: one-hot incidence, replaced by index math
    const float* W1 = (const float*)d_in[3];
    const float* b1 = (const float*)d_in[4];
    const float* W2 = (const float*)d_in[5];
    const float* b2 = (const float*)d_in[6];
    (void)d_ws; (void)ws_size; (void)in_sizes; (void)n_in; (void)out_size;
    float* out = (float*)d_out;

    nri_mlp_fused<<<2040, 256, 0, stream>>>(x, W1, b1, W2, b2, out);
}

// Round 4
// 280.418 us; speedup vs baseline: 1.2109x; 1.1169x over previous
//
#include <hip/hip_runtime.h>

// NRI edge-MLP encoder, fused single kernel (NO workspace):
// out[b,e,:] = relu(concat(x[b,send(e)], x[b,recv(e)]) @ W1^T + b1) @ W2^T + b2
// B=8, N=256, E=65280, n_in=64, n_hid=128, n_out=64.
// edge e: recv = e/255, k = e%255, send = k + (k >= recv)
//
// Round-3 post-mortem: WRITE_SIZE = 1.75x output (98MB scratch) survived the
// demand reduction; VGPR_Count pinned at 128 through launch_bounds(256,2) AND
// waves_per_eu(2,2) -> treat 128 arch VGPRs as this compiler's hard ceiling.
// w1f[4][8] resident (128 regs) + acc(32) + af(16) + biases(24) > 128 ->
// ~48 regs spilled per thread, reloaded per tile = the observed 192B/160B
// per-thread scratch traffic. Fix: DO NOT hold w1f resident. Stream W1
// fragments from LDS inside the MFMA loop, exactly as phase 2 already
// streams W2. Steady-state live set ~105 regs < 128 -> spill impossible.
// Extra cost: 32 ds_read_b128 per tile per wave (2-way-conflict pattern,
// ~4us of LDS pipe across the grid) -- noise vs 98MB of scratch round-trips.

using frag_t  = __attribute__((ext_vector_type(8))) short;          // 8 bf16 = 4 VGPRs
using f32x4   = __attribute__((ext_vector_type(4))) float;
using ushort8 = __attribute__((ext_vector_type(8))) unsigned short;

__device__ inline unsigned short f2bf(float f) {
    union { float f; unsigned u; } v; v.f = f;
    unsigned r = v.u + 0x7fffu + ((v.u >> 16) & 1u);   // RTNE
    return (unsigned short)(r >> 16);
}

__device__ inline ushort8 pack8(f32x4 a, f32x4 b) {
    ushort8 o;
    o[0] = f2bf(a[0]); o[1] = f2bf(a[1]); o[2] = f2bf(a[2]); o[3] = f2bf(a[3]);
    o[4] = f2bf(b[0]); o[5] = f2bf(b[1]); o[6] = f2bf(b[2]); o[7] = f2bf(b[3]);
    return o;
}

__device__ inline frag_t packfrag(f32x4 a, f32x4 b) {
    union { ushort8 u; frag_t f; } v; v.u = pack8(a, b); return v.f;
}

// grid 2040 = 8 batches x 255 blocks x 256 edges; wave owns 64 edges.
// One __syncthreads after the cooperative W stage; everything else per-wave.
__global__ __launch_bounds__(256)
void nri_mlp_fused(const float* __restrict__ x,
                   const float* __restrict__ W1,
                   const float* __restrict__ b1,
                   const float* __restrict__ W2,
                   const float* __restrict__ b2,
                   float* __restrict__ out) {
    __shared__ unsigned short W1s[128 * 128];    // 32 KB, swizzled bf16
    __shared__ unsigned short W2s[64 * 128];     // 16 KB, swizzled bf16
    __shared__ unsigned short Hs[4][16 * 128];   // 16 KB: per-wave 16-row H tile

    const int tid  = threadIdx.x;
    const int wave = tid >> 6;
    const int lane = tid & 63;
    const int quad = lane >> 4;
    const int n16  = lane & 15;

    const int bx = blockIdx.x;
    const int b  = bx / 255;
    const int eb = (bx - b * 255) * 256;
    const int e0 = eb + wave * 64;               // this wave's 64 edges

    const float* xb = x + b * (256 * 64);

    // ---- cooperative W1/W2 stage: fp32 -> bf16 -> swizzled LDS ----
    // chunk = 8 elems (16B bf16). Data chunk c of row r stored at slot c^(r&7).
    #pragma unroll
    for (int i = 0; i < 8; ++i) {                // W1: 2048 chunks / 256 thr
        int cid  = tid + i * 256;
        int row  = cid >> 4;                     // 0..127
        int c    = cid & 15;
        int slot = c ^ (row & 7);
        const float* s = W1 + row * 128 + c * 8;
        *(ushort8*)&W1s[row * 128 + slot * 8] =
            pack8(*(const f32x4*)s, *(const f32x4*)(s + 4));
    }
    #pragma unroll
    for (int i = 0; i < 4; ++i) {                // W2: 1024 chunks / 256 thr
        int cid  = tid + i * 256;
        int row  = cid >> 4;                     // 0..63
        int c    = cid & 15;
        int slot = c ^ (row & 7);
        const float* s = W2 + row * 128 + c * 8;
        *(ushort8*)&W2s[row * 128 + slot * 8] =
            pack8(*(const f32x4*)s, *(const f32x4*)(s + 4));
    }
    __syncthreads();

    float b1v[8];
    #pragma unroll
    for (int c = 0; c < 8; ++c) b1v[c] = b1[c * 16 + n16];
    float b2v[4][4];
    #pragma unroll
    for (int c2 = 0; c2 < 4; ++c2)
        #pragma unroll
        for (int ri = 0; ri < 4; ++ri)
            b2v[c2][ri] = b2[c2 * 16 + quad * 4 + ri];

    unsigned short* Hw = &Hs[wave][0];

    #pragma unroll 1   // contain register pressure: no cross-tile hoisting
    for (int t = 0; t < 4; ++t) {
        // A-operand row for this lane: edge e, features k = ks*32 + quad*8.
        // chunk = ks*4+quad: chunks 0..7 = sender feats, 8..15 = receiver.
        int e    = e0 + t * 16 + n16;
        int recv = e / 255;
        int kk   = e - recv * 255;
        int send = kk + (kk >= recv ? 1 : 0);

        frag_t af[4];
        #pragma unroll
        for (int ks = 0; ks < 4; ++ks) {
            int node = (ks < 2) ? send : recv;                    // ks<2 <=> chunk<8
            const float* s = xb + node * 64 + ((ks & 1) * 4 + quad) * 8;
            af[ks] = packfrag(*(const f32x4*)s, *(const f32x4*)(s + 4));
        }

        // ---- phase 1: H-tile = relu(A @ W1^T + b1), W1 frags STREAMED from LDS ----
        f32x4 acc[8];
        #pragma unroll
        for (int c = 0; c < 8; ++c) acc[c] = (f32x4){0.f, 0.f, 0.f, 0.f};
        #pragma unroll
        for (int ks = 0; ks < 4; ++ks) {
            #pragma unroll
            for (int c = 0; c < 8; ++c) {
                int row  = c * 16 + n16;
                int slot = (ks * 4 + quad) ^ (row & 7);
                frag_t w1 = *(const frag_t*)&W1s[row * 128 + slot * 8];
                acc[c] = __builtin_amdgcn_mfma_f32_16x16x32_bf16(af[ks], w1, acc[c], 0, 0, 0);
            }
        }

        // C-layout: col = n16 (hid feat c*16+n16), row = quad*4+ri (edge row 0..15)
        #pragma unroll
        for (int c = 0; c < 8; ++c) {
            float bv = b1v[c];
            #pragma unroll
            for (int ri = 0; ri < 4; ++ri) {
                float v = acc[c][ri] + bv;
                v = v > 0.f ? v : 0.f;
                int row  = quad * 4 + ri;
                int k    = c * 16 + n16;
                int slot = (k >> 3) ^ (row & 7);
                Hw[row * 128 + slot * 8 + (n16 & 7)] = f2bf(v);
            }
        }

        // ---- phase 2: out-tile^T = W2 @ H^T (w2 frags streamed from LDS) ----
        f32x4 acc2[4];
        #pragma unroll
        for (int c2 = 0; c2 < 4; ++c2) acc2[c2] = (f32x4){0.f, 0.f, 0.f, 0.f};
        #pragma unroll
        for (int ks = 0; ks < 4; ++ks) {
            int hslot = (ks * 4 + quad) ^ (n16 & 7);   // H row = n16; W2 row&7 = n16&7
            frag_t hf = *(const frag_t*)&Hw[n16 * 128 + hslot * 8];
            #pragma unroll
            for (int c2 = 0; c2 < 4; ++c2) {
                int row = c2 * 16 + n16;
                frag_t w2 = *(const frag_t*)&W2s[row * 128 + hslot * 8];
                acc2[c2] = __builtin_amdgcn_mfma_f32_16x16x32_bf16(w2, hf, acc2[c2], 0, 0, 0);
            }
        }

        // C-layout: col = n16 = edge, row = quad*4+ri = out-feature -> float4 store
        float* ob = out + ((long)b * 65280 + e0 + t * 16 + n16) * 64;
        #pragma unroll
        for (int c2 = 0; c2 < 4; ++c2) {
            f32x4 v;
            #pragma unroll
            for (int ri = 0; ri < 4; ++ri) v[ri] = acc2[c2][ri] + b2v[c2][ri];
            *(f32x4*)&ob[c2 * 16 + quad * 4] = v;
        }
    }
}

extern "C" void kernel_launch(void* const* d_in, const int* in_sizes, int n_in,
                              void* d_out, int out_size, void* d_ws, size_t ws_size,
                              hipStream_t stream) {
    const float* x  = (const float*)d_in[0];
    // d_in[1] = rel_rec, d_in[2] = rel_send: one-hot incidence, replaced by index math
    const float* W1 = (const float*)d_in[3];
    const float* b1 = (const float*)d_in[4];
    const float* W2 = (const float*)d_in[5];
    const float* b2 = (const float*)d_in[6];
    (void)d_ws; (void)ws_size; (void)in_sizes; (void)n_in; (void)out_size;
    float* out = (float*)d_out;

    nri_mlp_fused<<<2040, 256, 0, stream>>>(x, W1, b1, W2, b2, out);
}

// Round 5
// 258.192 us; speedup vs baseline: 1.3151x; 1.0861x over previous
//
#include <hip/hip_runtime.h>

// NRI edge-MLP encoder, fused single kernel (NO workspace):
// out[b,e,:] = relu(concat(x[b,send(e)], x[b,recv(e)]) @ W1^T + b1) @ W2^T + b2
// B=8, N=256, E=65280, n_in=64, n_hid=128, n_out=64.
// edge e: recv = e/255, k = e%255, send = k + (k >= recv)
//
// Round-4 post-mortem: spill gone (WRITE_SIZE == output exactly), kernel
// 101us but latency-bound: ~84 LDS ops/tile/wave (32 W1 reads + 32 scalar
// H writes + lgkm drain + 20 reads) with only 8 waves/CU (64KB LDS).
// Round-5 structure: H never touches LDS.
//  (a) phase 1 swaps MFMA operands: mfma(w1, af) -> Ht[hid][edge], lane
//      n16 = edge (same lane owns the edge in both phases).
//  (b) phase 2 k-dim is PERMUTED: pi(32ks+8q+j) = 32ks+16(j>>2)+4q+(j&3).
//      W2 is stored in LDS in pi-order (applied at cooperative staging:
//      two f32x4 loads at base, base+16). Under pi, the phase-2 B-frag is
//      concat(pack4(acc[2ks]), pack4(acc[2ks+1])) -- built IN-LANE from
//      phase-1 accumulators. Zero cross-lane ops, zero H traffic.
//  (c) biases fold into accumulator init (acc=b1v4, acc2=b2v4).
// LDS = 32K(W1) + 16K(W2-permuted) = 48KB -> 3 blocks/CU (12 waves).
// Per tile: 48 ds_read_b128, 0 ds_writes, 48 MFMA. Reg peak ~128.

using frag_t  = __attribute__((ext_vector_type(8))) short;          // 8 bf16 = 4 VGPRs
using f32x4   = __attribute__((ext_vector_type(4))) float;
using ushort8 = __attribute__((ext_vector_type(8))) unsigned short;

__device__ inline unsigned short f2bf(float f) {
    union { float f; unsigned u; } v; v.f = f;
    unsigned r = v.u + 0x7fffu + ((v.u >> 16) & 1u);   // RTNE
    return (unsigned short)(r >> 16);
}

__device__ inline ushort8 pack8(f32x4 a, f32x4 b) {
    ushort8 o;
    o[0] = f2bf(a[0]); o[1] = f2bf(a[1]); o[2] = f2bf(a[2]); o[3] = f2bf(a[3]);
    o[4] = f2bf(b[0]); o[5] = f2bf(b[1]); o[6] = f2bf(b[2]); o[7] = f2bf(b[3]);
    return o;
}

__device__ inline frag_t packfrag(f32x4 a, f32x4 b) {
    union { ushort8 u; frag_t f; } v; v.u = pack8(a, b); return v.f;
}

// grid 2040 = 8 batches x 255 blocks x 256 edges; wave owns 64 edges.
// One __syncthreads after the cooperative W stage; everything else per-wave.
__global__ __launch_bounds__(256)
void nri_mlp_fused(const float* __restrict__ x,
                   const float* __restrict__ W1,
                   const float* __restrict__ b1,
                   const float* __restrict__ W2,
                   const float* __restrict__ b2,
                   float* __restrict__ out) {
    __shared__ unsigned short W1s[128 * 128];    // 32 KB, swizzled bf16
    __shared__ unsigned short W2s[64 * 128];     // 16 KB, pi-permuted + swizzled bf16

    const int tid  = threadIdx.x;
    const int wave = tid >> 6;
    const int lane = tid & 63;
    const int quad = lane >> 4;
    const int n16  = lane & 15;

    const int bx = blockIdx.x;
    const int b  = bx / 255;
    const int eb = (bx - b * 255) * 256;
    const int e0 = eb + wave * 64;               // this wave's 64 edges

    const float* xb = x + b * (256 * 64);

    // ---- cooperative W1/W2 stage: fp32 -> bf16 -> swizzled LDS ----
    // chunk = 8 elems (16B bf16); data chunk c of row r stored at slot c^(r&7).
    #pragma unroll
    for (int i = 0; i < 8; ++i) {                // W1: 2048 chunks / 256 thr
        int cid  = tid + i * 256;
        int row  = cid >> 4;                     // 0..127 (hid)
        int c    = cid & 15;
        int slot = c ^ (row & 7);
        const float* s = W1 + row * 128 + c * 8;
        *(ushort8*)&W1s[row * 128 + slot * 8] =
            pack8(*(const f32x4*)s, *(const f32x4*)(s + 4));
    }
    // W2 stored by PERMUTED k-position p: pi(32ks+8q+j) = 32ks+16(j>>2)+4q+(j&3).
    // Position-chunk c (=4ks+q) holds hids base+{0..3,16..19}, base=32(c>>2)+4(c&3).
    #pragma unroll
    for (int i = 0; i < 4; ++i) {                // W2: 1024 chunks / 256 thr
        int cid  = tid + i * 256;
        int row  = cid >> 4;                     // 0..63 (out-feat)
        int c    = cid & 15;                     // position-chunk
        int slot = c ^ (row & 7);
        int base = 32 * (c >> 2) + 4 * (c & 3);
        const float* s = W2 + row * 128 + base;
        *(ushort8*)&W2s[row * 128 + slot * 8] =
            pack8(*(const f32x4*)s, *(const f32x4*)(s + 16));
    }
    __syncthreads();

    // bias vectors fold into accumulator init:
    // phase-1 acc[c][ri] covers hid = 16c + 4*quad + ri  -> b1v4[c] = b1[16c+4q ..]
    // phase-2 acc2[c2][ri] covers out = 16c2 + 4*quad + ri -> b2v4[c2]
    f32x4 b1v4[8];
    #pragma unroll
    for (int c = 0; c < 8; ++c) b1v4[c] = *(const f32x4*)(b1 + c * 16 + quad * 4);
    f32x4 b2v4[4];
    #pragma unroll
    for (int c2 = 0; c2 < 4; ++c2) b2v4[c2] = *(const f32x4*)(b2 + c2 * 16 + quad * 4);

    #pragma unroll 1   // contain register pressure: no cross-tile hoisting
    for (int t = 0; t < 4; ++t) {
        // This lane's edge: e = e0 + t*16 + n16 (lane n16 = edge in BOTH phases).
        int e    = e0 + t * 16 + n16;
        int recv = e / 255;
        int kk   = e - recv * 255;
        int send = kk + (kk >= recv ? 1 : 0);

        // B-operand (edges): lane holds E[edge=n16][k = ks*32 + quad*8 ..+8]
        frag_t af[4];
        #pragma unroll
        for (int ks = 0; ks < 4; ++ks) {
            int node = (ks < 2) ? send : recv;                    // k<64 <=> sender
            const float* s = xb + node * 64 + ((ks & 1) * 4 + quad) * 8;
            af[ks] = packfrag(*(const f32x4*)s, *(const f32x4*)(s + 4));
        }

        // ---- phase 1: Ht = W1 @ E^T + b1. A = W1 rows (streamed from LDS),
        // B = af. C-layout: col = n16 = edge, row = quad*4+ri = hid (per 16-blk c).
        f32x4 acc[8];
        #pragma unroll
        for (int c = 0; c < 8; ++c) acc[c] = b1v4[c];
        #pragma unroll
        for (int ks = 0; ks < 4; ++ks) {
            #pragma unroll
            for (int c = 0; c < 8; ++c) {
                int row  = c * 16 + n16;
                int slot = (ks * 4 + quad) ^ (row & 7);
                frag_t w1 = *(const frag_t*)&W1s[row * 128 + slot * 8];
                acc[c] = __builtin_amdgcn_mfma_f32_16x16x32_bf16(w1, af[ks], acc[c], 0, 0, 0);
            }
        }

        // ---- relu + in-lane repack to phase-2 B-frags (the pi trick):
        // hf[ks] = [pack4(acc[2ks]), pack4(acc[2ks+1])] -- no cross-lane moves.
        frag_t hf[4];
        #pragma unroll
        for (int ks = 0; ks < 4; ++ks) {
            f32x4 lo = acc[2 * ks], hi = acc[2 * ks + 1];
            #pragma unroll
            for (int ri = 0; ri < 4; ++ri) {
                lo[ri] = lo[ri] > 0.f ? lo[ri] : 0.f;
                hi[ri] = hi[ri] > 0.f ? hi[ri] : 0.f;
            }
            hf[ks] = packfrag(lo, hi);
        }

        // ---- phase 2: out^T = W2 @ H^T + b2, k in pi-order on both operands.
        f32x4 acc2[4];
        #pragma unroll
        for (int c2 = 0; c2 < 4; ++c2) acc2[c2] = b2v4[c2];
        #pragma unroll
        for (int ks = 0; ks < 4; ++ks) {
            #pragma unroll
            for (int c2 = 0; c2 < 4; ++c2) {
                int row  = c2 * 16 + n16;
                int slot = (ks * 4 + quad) ^ (row & 7);
                frag_t w2 = *(const frag_t*)&W2s[row * 128 + slot * 8];
                acc2[c2] = __builtin_amdgcn_mfma_f32_16x16x32_bf16(w2, hf[ks], acc2[c2], 0, 0, 0);
            }
        }

        // C-layout: col = n16 = edge, row = quad*4+ri = out-feature -> float4 store
        float* ob = out + ((long)b * 65280 + e) * 64;
        #pragma unroll
        for (int c2 = 0; c2 < 4; ++c2)
            *(f32x4*)&ob[c2 * 16 + quad * 4] = acc2[c2];
    }
}

extern "C" void kernel_launch(void* const* d_in, const int* in_sizes, int n_in,
                              void* d_out, int out_size, void* d_ws, size_t ws_size,
                              hipStream_t stream) {
    const float* x  = (const float*)d_in[0];
    // d_in[1] = rel_rec, d_in[2] = rel_send: one-hot incidence, replaced by index math
    const float* W1 = (const float*)d_in[3];
    const float* b1 = (const float*)d_in[4];
    const float* W2 = (const float*)d_in[5];
    const float* b2 = (const float*)d_in[6];
    (void)d_ws; (void)ws_size; (void)in_sizes; (void)n_in; (void)out_size;
    float* out = (float*)d_out;

    nri_mlp_fused<<<2040, 256, 0, stream>>>(x, W1, b1, W2, b2, out);
}